// Round 6
// baseline (43.722 us; speedup 1.0000x reference)
//
#include <hip/hip_runtime.h>
#include <math.h>

#define SDIM 512
#define DDIM 256
#define NBATCH 4
#define SSQ (SDIM*SDIM)            // 262144
#define MED_K ((SSQ-1)/2)          // 131071
#define NBINS 4096
#define HMAX 48.0f                 // fixed histogram range [0, HMAX)
#define PADK 264                   // bf16 LDS row stride (16B-aligned rows, 2-way bank = free)
#define NTILES 36                  // 8*9/2 upper-tri 64x64 tiles

// ---- workspace layout (bytes) ----
#define OFF_DISTS   0ull                               // 2 MB: u16 bins [4][512][512]
#define OFF_HIST    (4ull<<20)                         // 32 KB used: packed u32[4][2048]
#define OFF_STATS   ((4ull<<20) + 65536ull)            // 128 B: per batch {sum,sumsq}dbl + {max,conn,thr,done}u32
#define OFF_SIGNAL  ((4ull<<20) + 65664ull)            // 4 KB: float[4][256]
#define OFF_ADJ     ((4ull<<20) + 69760ull)            // 128 KB: u64[4][512][8]
#define NZERO ((65536 + 128) / 4)                      // zero hist region + stats

typedef __attribute__((ext_vector_type(8))) short short8_t;
typedef __attribute__((ext_vector_type(4))) float f32x4_t;

__device__ __forceinline__ unsigned short f2bf(float f) {
    unsigned u = __float_as_uint(f);
    return (unsigned short)((u + 0x7FFFu + ((u >> 16) & 1u)) >> 16);   // RNE
}

// ---------------------------------------------------------------------------
// 0) zero hist+stats
__global__ __launch_bounds__(256) void k_zero(unsigned* __restrict__ z) {
    const int i = blockIdx.x * 256 + threadIdx.x;
    if (i < NZERO) z[i] = 0u;
}

// ---------------------------------------------------------------------------
// 1) pairwise distances, UPPER-TRI tiles only (36/batch), bf16 MFMA Gram.
//    d^2 = |a|^2+|b|^2-2G; stores u16 bin indices; mirror tile written via
//    LDS transpose (coalesced). Fused: packed LDS hist (weight 2 off-diag),
//    triu sum/sumsq/max, and median-bucket selection in the LAST block per
//    batch (done-counter + device fence; deterministic: complete hist).
__global__ __launch_bounds__(256) void k_dist(const float* __restrict__ x,
                                              unsigned short* __restrict__ udists,
                                              double* __restrict__ stats,
                                              unsigned* __restrict__ ghist) {
    const int b = blockIdx.y;
    int idx = blockIdx.x, ti = 0;
    while (idx >= 8 - ti) { idx -= 8 - ti; ++ti; }
    const int tj = ti + idx;
    const bool diag = (ti == tj);
    const int i0 = ti * 64, j0 = tj * 64;

    __shared__ __align__(16) unsigned short Ab[64 * PADK];   // 33 KB
    __shared__ __align__(16) unsigned short Bb[64 * PADK];   // 33 KB
    __shared__ unsigned lh[NBINS / 2];                       // 8 KB packed (2 bins/u32)
    __shared__ float nA[64], nB[64];
    __shared__ unsigned psum[256];
    __shared__ int lastflag;
    __shared__ float wm[4];
    __shared__ double wsm[4], wq[4];
    unsigned short* trn = Ab;                                // alias after MFMA reads done
    const int tid = threadIdx.x;
    const float* xb = x + (size_t)b * SDIM * DDIM;

    for (int t = tid; t < NBINS / 2; t += 256) lh[t] = 0u;

    // ---- stage tiles as bf16 + f32 row norms ----
    {
        const int r = tid >> 2, sub = tid & 3;
        const float* arow = xb + (size_t)(i0 + r) * DDIM + sub * 64;
        const float* brow = xb + (size_t)(j0 + r) * DDIM + sub * 64;
        float nap = 0.f, nbp = 0.f;
#pragma unroll
        for (int q = 0; q < 16; ++q) {
            float4 a4 = *(const float4*)(arow + q * 4);
            float4 b4 = *(const float4*)(brow + q * 4);
            nap += a4.x * a4.x + a4.y * a4.y + a4.z * a4.z + a4.w * a4.w;
            nbp += b4.x * b4.x + b4.y * b4.y + b4.z * b4.z + b4.w * b4.w;
            ushort4 ap = { f2bf(a4.x), f2bf(a4.y), f2bf(a4.z), f2bf(a4.w) };
            ushort4 bp = { f2bf(b4.x), f2bf(b4.y), f2bf(b4.z), f2bf(b4.w) };
            *(ushort4*)&Ab[r * PADK + sub * 64 + q * 4] = ap;
            *(ushort4*)&Bb[r * PADK + sub * 64 + q * 4] = bp;
        }
        nap += __shfl_xor(nap, 1); nap += __shfl_xor(nap, 2);
        nbp += __shfl_xor(nbp, 1); nbp += __shfl_xor(nbp, 2);
        if (sub == 0) { nA[r] = nap; nB[r] = nbp; }
    }
    __syncthreads();

    // ---- MFMA Gram ----
    const int w = tid >> 6, l = tid & 63;
    const int lrow = l & 15, lkb = l >> 4;
    f32x4_t ac0 = {0.f, 0.f, 0.f, 0.f}, ac1 = ac0, ac2 = ac0, ac3 = ac0;
    const unsigned short* Ap  = &Ab[(w * 16 + lrow) * PADK + lkb * 8];
    const unsigned short* Bp0 = &Bb[(0  + lrow) * PADK + lkb * 8];
    const unsigned short* Bp1 = &Bb[(16 + lrow) * PADK + lkb * 8];
    const unsigned short* Bp2 = &Bb[(32 + lrow) * PADK + lkb * 8];
    const unsigned short* Bp3 = &Bb[(48 + lrow) * PADK + lkb * 8];
#pragma unroll
    for (int ks = 0; ks < 8; ++ks) {
        short8_t af = *(const short8_t*)(Ap  + ks * 32);
        short8_t b0 = *(const short8_t*)(Bp0 + ks * 32);
        short8_t b1 = *(const short8_t*)(Bp1 + ks * 32);
        short8_t b2 = *(const short8_t*)(Bp2 + ks * 32);
        short8_t b3 = *(const short8_t*)(Bp3 + ks * 32);
        ac0 = __builtin_amdgcn_mfma_f32_16x16x32_bf16(af, b0, ac0, 0, 0, 0);
        ac1 = __builtin_amdgcn_mfma_f32_16x16x32_bf16(af, b1, ac1, 0, 0, 0);
        ac2 = __builtin_amdgcn_mfma_f32_16x16x32_bf16(af, b2, ac2, 0, 0, 0);
        ac3 = __builtin_amdgcn_mfma_f32_16x16x32_bf16(af, b3, ac3, 0, 0, 0);
    }
    __syncthreads();                  // MFMA LDS reads done -> Ab reusable as trn

    // ---- epilogue: d, u16 bin store, hist, triu stats, max, trn ----
    unsigned short* udb = udists + (size_t)b * SSQ;
    const float hscale = (float)NBINS / HMAX;
    const unsigned wgt = diag ? 1u : 2u;
    const int orow = w * 16 + lkb * 4;
    float bm = 0.f, fsum = 0.f, fsumsq = 0.f;
#pragma unroll
    for (int c = 0; c < 4; ++c) {
        const f32x4_t a = (c == 0) ? ac0 : (c == 1) ? ac1 : (c == 2) ? ac2 : ac3;
        const int jl = c * 16 + lrow;
        const float njv = nB[jl];
        const int gj = j0 + jl;
#pragma unroll
        for (int reg = 0; reg < 4; ++reg) {
            const int il = orow + reg;
            const int gi = i0 + il;
            float sq = fmaf(-2.0f, a[reg], nA[il] + njv);
            float d  = sq > 0.f ? sqrtf(sq) : 0.f;
            if (gi == gj) d = 0.f;
            bm = fmaxf(bm, d);
            int bin = (int)(d * hscale);
            bin = bin > (NBINS - 1) ? (NBINS - 1) : bin;
            udb[(size_t)gi * SDIM + gj] = (unsigned short)bin;
            atomicAdd(&lh[bin >> 1], (bin & 1) ? (wgt << 16) : wgt);
            if (diag) { if (gj >= gi) { fsum += d; fsumsq += d * d; } }
            else      { fsum += d; fsumsq += d * d; }
            if (!diag) trn[jl * 72 + il] = (unsigned short)bin;
        }
    }
    __syncthreads();
    if (!diag) {      // coalesced mirror store: rows j0.., cols i0..
        for (int t = tid; t < 64 * 8; t += 256) {
            const int r = t >> 3, ch = t & 7;
            *(uint4*)&udb[(size_t)(j0 + r) * SDIM + i0 + ch * 8] =
                *(const uint4*)&trn[r * 72 + ch * 8];
        }
    }

    // ---- block reductions -> global stats ----
    double s = (double)fsum, q = (double)fsumsq;
#pragma unroll
    for (int off = 32; off; off >>= 1) {
        bm = fmaxf(bm, __shfl_xor(bm, off));
        s += __shfl_xor(s, off);
        q += __shfl_xor(q, off);
    }
    if (l == 0) { wm[w] = bm; wsm[w] = s; wq[w] = q; }
    __syncthreads();
    double* st = stats + (size_t)b * 4;
    unsigned* sw = (unsigned*)st;
    if (tid == 0) {
        float m = fmaxf(fmaxf(wm[0], wm[1]), fmaxf(wm[2], wm[3]));
        atomicMax(&sw[4], __float_as_uint(m));
        atomicAdd(&st[0], wsm[0] + wsm[1] + wsm[2] + wsm[3]);
        atomicAdd(&st[1], wq[0] + wq[1] + wq[2] + wq[3]);
    }
    unsigned* gh = ghist + (size_t)b * (NBINS / 2);
    for (int t = tid; t < NBINS / 2; t += 256) {
        unsigned v = lh[t];
        if (v) atomicAdd(&gh[t], v);
    }
    __threadfence();
    if (tid == 0) lastflag = (atomicAdd(&sw[7], 1u) == NTILES - 1);
    __syncthreads();

    // ---- last block per batch: median bucket from complete hist ----
    if (lastflag) {
        unsigned cnt[16]; unsigned local = 0;
#pragma unroll
        for (int qq = 0; qq < 8; ++qq) {
            unsigned pw = atomicOr(&gh[tid * 8 + qq], 0u);   // coherent read
            cnt[2 * qq] = pw & 0xffffu; cnt[2 * qq + 1] = pw >> 16;
            local += cnt[2 * qq] + cnt[2 * qq + 1];
        }
        psum[tid] = local;
        __syncthreads();
        for (int off = 1; off < 256; off <<= 1) {
            unsigned v = 0;
            if (tid >= off) v = psum[tid - off];
            __syncthreads();
            psum[tid] += v;
            __syncthreads();
        }
        const unsigned excl = psum[tid] - local;
        if (MED_K >= excl && MED_K < excl + local) {
            unsigned run = excl;
            int bucket = tid * 16;
            for (int t = 0; t < 16; ++t) {
                if (MED_K < run + cnt[t]) { bucket = tid * 16 + t; break; }
                run += cnt[t];
            }
            sw[6] = (unsigned)bucket;         // thr bucket: pred is (bin < bucket)
        }
    }
}

// ---------------------------------------------------------------------------
// 2) adjacency from u16 bins: ballot bitmask + edge count. 8 rows/block.
__global__ __launch_bounds__(256) void k_adj(const unsigned short* __restrict__ ud,
                                             unsigned long long* __restrict__ adj,
                                             double* __restrict__ stats) {
    const int b = blockIdx.y, tid = threadIdx.x;
    unsigned* sw = (unsigned*)(stats + (size_t)b * 4);
    const unsigned bucket = sw[6];
    const int w = tid >> 6, lane = tid & 63;
    int conn = 0;
#pragma unroll
    for (int rr = 0; rr < 2; ++rr) {
        const int i = blockIdx.x * 8 + w * 2 + rr;
        const unsigned short* row = ud + (size_t)b * SSQ + (size_t)i * SDIM;
        unsigned long long words[8];
#pragma unroll
        for (int c = 0; c < 8; ++c) {
            const int j = c * 64 + lane;
            const bool pred = (row[j] < bucket) && (j != i);
            words[c] = __ballot(pred ? 1 : 0);
            conn += pred ? 1 : 0;
        }
        if (lane == 0) {
#pragma unroll
            for (int c = 0; c < 8; ++c) adj[((size_t)b * SDIM + i) * 8 + c] = words[c];
        }
    }
#pragma unroll
    for (int off = 32; off; off >>= 1) conn += __shfl_xor(conn, off);
    __shared__ int sh_c[4];
    if (lane == 0) sh_c[w] = conn;
    __syncthreads();
    if (tid == 0)
        atomicAdd(&sw[5], (unsigned)(sh_c[0] + sh_c[1] + sh_c[2] + sh_c[3]));
}

// ---------------------------------------------------------------------------
// 3) connected components by ballot-BFS + topo-feature matvec (signal).
__global__ __launch_bounds__(512) void k_ccsig(const uint4* __restrict__ adj,
                                               const double* __restrict__ stats,
                                               const float* __restrict__ W,
                                               const float* __restrict__ bias,
                                               float* __restrict__ signal) {
    const int b = blockIdx.x;
    __shared__ uint4 am[SDIM][4];
    __shared__ unsigned frontW[16], reachW[16];
    __shared__ int s_next, s_ncomp, s_any;
    const int tid = threadIdx.x;
    const uint4* ab = adj + (size_t)b * SDIM * 4;
    for (int t = tid; t < SDIM * 4; t += 512) ((uint4*)am)[t] = ab[t];
    if (tid < 16) { frontW[tid] = 0u; reachW[tid] = 0u; }
    if (tid == 0) s_ncomp = 0;
    __syncthreads();

    bool myReached = false;
    for (int comp = 0; comp < SDIM; ++comp) {
        if (tid == 0) {
            int s = -1;
            for (int w = 0; w < 16 && s < 0; ++w) {
                unsigned m = ~reachW[w];
                if (m) s = w * 32 + __ffs(m) - 1;
            }
            s_next = s;
            if (s >= 0) s_ncomp++;
        }
        __syncthreads();
        const int s = s_next;
        if (s < 0) break;
        if (tid < 16) {
            unsigned f = (tid == (s >> 5)) ? (1u << (s & 31)) : 0u;
            frontW[tid] = f;
            reachW[tid] |= f;
        }
        if (tid == s) myReached = true;
        __syncthreads();

        for (int it = 0; it < SDIM; ++it) {
            const uint4 f0 = *(const uint4*)&frontW[0];
            const uint4 f1 = *(const uint4*)&frontW[4];
            const uint4 f2 = *(const uint4*)&frontW[8];
            const uint4 f3 = *(const uint4*)&frontW[12];
            const uint4 r0 = am[tid][0], r1 = am[tid][1];
            const uint4 r2 = am[tid][2], r3 = am[tid][3];
            const unsigned inter =
                (r0.x & f0.x) | (r0.y & f0.y) | (r0.z & f0.z) | (r0.w & f0.w) |
                (r1.x & f1.x) | (r1.y & f1.y) | (r1.z & f1.z) | (r1.w & f1.w) |
                (r2.x & f2.x) | (r2.y & f2.y) | (r2.z & f2.z) | (r2.w & f2.w) |
                (r3.x & f3.x) | (r3.y & f3.y) | (r3.z & f3.z) | (r3.w & f3.w);
            const bool act = (inter != 0u) && !myReached;
            const unsigned long long bal = __ballot(act ? 1 : 0);
            __syncthreads();
            if ((tid & 63) == 0) {
                const int wv = tid >> 6;
                frontW[wv * 2]     = (unsigned)bal;
                frontW[wv * 2 + 1] = (unsigned)(bal >> 32);
            }
            if (tid == 0) s_any = 0;
            __syncthreads();
            if (act) myReached = true;
            if (tid < 16) {
                unsigned nf = frontW[tid];
                reachW[tid] |= nf;
                if (nf) atomicOr(&s_any, 1);
            }
            __syncthreads();
            if (!s_any) break;
        }
    }
    __syncthreads();

    if (tid < DDIM) {
        const double* st = stats + (size_t)b * 4;
        const unsigned* sw = (const unsigned*)st;
        const double sum = st[0], sumsq = st[1];
        const unsigned maxbits = sw[4], conn = sw[5];
        const double cntf = (double)(SDIM * (SDIM + 1) / 2);
        const double mean = sum / cntf;
        double var = (sumsq - sum * sum / cntf) / (cntf - 1.0);
        var = var > 0.0 ? var : 0.0;
        const float t0 = (float)((double)conn / (double)(SDIM * (SDIM - 1)));
        const float t1 = (float)s_ncomp / (float)SDIM;
        const float t2 = (float)((double)conn / (double)(SDIM * SDIM));
        const float t3 = (float)mean;
        const float t4 = (float)sqrt(var);
        const float t6 = __uint_as_float(maxbits);
        const float* w = W + tid * 8;
        signal[b * DDIM + tid] = bias[tid] + t0 * w[0] + t1 * w[1] + t2 * w[2]
                               + t3 * w[3] + t4 * w[4] + t6 * w[6];
    }
}

// ---------------------------------------------------------------------------
// 4) residual + LayerNorm, wave per row
__global__ __launch_bounds__(256) void k_ln(const float* __restrict__ x,
                                            const float* __restrict__ signal,
                                            const float* __restrict__ gamma,
                                            const float* __restrict__ beta,
                                            float* __restrict__ out) {
    const int tid = threadIdx.x;
    const int w = tid >> 6, lane = tid & 63;
    const int row = blockIdx.x * 4 + w;
    const int b = row >> 9;
    const float4 xv = *(const float4*)(x + (size_t)row * DDIM + lane * 4);
    const float4 sg = *(const float4*)(signal + (size_t)b * DDIM + lane * 4);
    float h0 = xv.x + sg.x, h1 = xv.y + sg.y, h2 = xv.z + sg.z, h3 = xv.w + sg.w;
    float s = h0 + h1 + h2 + h3;
#pragma unroll
    for (int off = 32; off; off >>= 1) s += __shfl_xor(s, off);
    const float mu = s * (1.0f / 256.0f);
    const float d0 = h0 - mu, d1 = h1 - mu, d2 = h2 - mu, d3 = h3 - mu;
    float q = d0 * d0 + d1 * d1 + d2 * d2 + d3 * d3;
#pragma unroll
    for (int off = 32; off; off >>= 1) q += __shfl_xor(q, off);
    const float var = q * (1.0f / 256.0f);
    const float r = 1.0f / sqrtf(var + 1e-5f);
    const float4 g  = *(const float4*)(gamma + lane * 4);
    const float4 be = *(const float4*)(beta + lane * 4);
    float4 o;
    o.x = d0 * r * g.x + be.x;
    o.y = d1 * r * g.y + be.y;
    o.z = d2 * r * g.z + be.z;
    o.w = d3 * r * g.w + be.w;
    *(float4*)(out + (size_t)row * DDIM + lane * 4) = o;
}

// ---------------------------------------------------------------------------
extern "C" void kernel_launch(void* const* d_in, const int* in_sizes, int n_in,
                              void* d_out, int out_size, void* d_ws, size_t ws_size,
                              hipStream_t stream) {
    (void)in_sizes; (void)n_in; (void)out_size; (void)ws_size;
    const float* x     = (const float*)d_in[0];
    const float* W     = (const float*)d_in[1];
    const float* bias  = (const float*)d_in[2];
    const float* gamma = (const float*)d_in[3];
    const float* beta  = (const float*)d_in[4];
    float* out = (float*)d_out;

    char* ws = (char*)d_ws;
    unsigned short* udists = (unsigned short*)(ws + OFF_DISTS);
    unsigned* ghist  = (unsigned*)(ws + OFF_HIST);
    double*   stats  = (double*)(ws + OFF_STATS);
    float*    signal = (float*)(ws + OFF_SIGNAL);
    unsigned long long* adj = (unsigned long long*)(ws + OFF_ADJ);

    k_zero  <<<(NZERO + 255) / 256,    256, 0, stream>>>((unsigned*)(ws + OFF_HIST));
    k_dist  <<<dim3(NTILES, NBATCH),   256, 0, stream>>>(x, udists, stats, ghist);
    k_adj   <<<dim3(64, NBATCH),       256, 0, stream>>>(udists, adj, stats);
    k_ccsig <<<NBATCH,                 512, 0, stream>>>((const uint4*)adj, stats, W, bias, signal);
    k_ln    <<<512,                    256, 0, stream>>>(x, signal, gamma, beta, out);
}